// Round 7
// baseline (823.080 us; speedup 1.0000x reference)
//
#include <hip/hip_runtime.h>
#include <stdint.h>

#define TOK 65536
#define DMODEL 768

typedef short  s16x8 __attribute__((ext_vector_type(8)));
typedef __bf16 bf16x8 __attribute__((ext_vector_type(8)));
typedef float  f32x4 __attribute__((ext_vector_type(4)));

__device__ __forceinline__ float b2f(unsigned short u) {
  union { unsigned int i; float f; } v; v.i = ((unsigned int)u) << 16; return v.f;
}
__device__ __forceinline__ unsigned short f2b(float f) {
  union { float f; unsigned int i; } v; v.f = f;
  unsigned int r = v.i + 0x7fffu + ((v.i >> 16) & 1u);
  return (unsigned short)(r >> 16);
}
// reduce within a 32-lane token group (xor-based, stays inside the group)
__device__ __forceinline__ float wsum32(float v) {
#pragma unroll
  for (int off = 16; off >= 1; off >>= 1) v += __shfl_xor(v, off, 64);
  return v;
}

// ---------------- GEMM: C[M,N] = A[M,K] @ W[N,K](bf16)^T (+bias) ----------------
// 128x128 tile, BK=64, 4 waves (2x2), mfma_f32_16x16x32_bf16, T2 XOR-swizzled LDS
// (both-sides involution), T3-minimum double-buffer: STAGE(t+1) issued BEFORE
// compute(t); ONE __syncthreads per K-step (its vmcnt(0)/lgkmcnt(0) is the drain).
// A_F32: A is fp32 in global; reg-stage (load->cvt->swizzled ds_write) kills cast_x.
template <bool BF16_OUT, bool HAS_BIAS, bool A_F32>
__global__ __launch_bounds__(256) void gemm_bt(const void* __restrict__ Av,
                        const unsigned short* __restrict__ W,
                        void* __restrict__ Cv,
                        const float* __restrict__ bias,
                        int M, int N, int K, int nt) {
  __shared__ __align__(16) unsigned short As[2][128 * 64];
  __shared__ __align__(16) unsigned short Bs[2][128 * 64];
  const int tid  = threadIdx.x;
  const int lane = tid & 63;
  const int w    = tid >> 6;      // wave 0..3
  const int wr   = w >> 1, wc = w & 1;
  const int l16  = lane & 15, lh = lane >> 4;

  const int per = gridDim.x >> 3;       // gridDim.x % 8 == 0
  const int bid = blockIdx.x;
  const int wg  = (bid & 7) * per + (bid >> 3);
  const long arow0 = (long)(wg / nt) * 128;
  const long bcol0 = (long)(wg % nt) * 128;

  const int srow = lane >> 3;                   // 0..7 within an 8-row section
  const int scol = ((lane & 7) ^ srow) * 8;     // pre-swizzled global chunk

  // f32-A reg staging: thread -> (row, 4 chunks of 8 elems)
  const int ar  = tid >> 1;          // 0..127
  const int ac0 = (tid & 1) * 4;     // chunk base 0 or 4

  const unsigned short* Au = (const unsigned short*)Av;
  const float* Af = (const float*)Av;

  f32x4 acc[4][4];
#pragma unroll
  for (int mi = 0; mi < 4; ++mi)
#pragma unroll
    for (int ni = 0; ni < 4; ++ni) acc[mi][ni] = f32x4{0.f, 0.f, 0.f, 0.f};

  float4 areg[8];

  auto stage_b = [&](int b, int k0) {
#pragma unroll
    for (int i = 0; i < 4; ++i) {
      int sec = i * 4 + w;
      int row = sec * 8 + srow;
      const unsigned short* gb = W + (bcol0 + row) * (long)K + k0 + scol;
      __builtin_amdgcn_global_load_lds(
          (const __attribute__((address_space(1))) void*)gb,
          (__attribute__((address_space(3))) void*)&Bs[b][sec * 512], 16, 0, 0);
    }
  };
  auto stage_a_lds = [&](int b, int k0) {
#pragma unroll
    for (int i = 0; i < 4; ++i) {
      int sec = i * 4 + w;
      int row = sec * 8 + srow;
      const unsigned short* ga = Au + (arow0 + row) * (long)K + k0 + scol;
      __builtin_amdgcn_global_load_lds(
          (const __attribute__((address_space(1))) void*)ga,
          (__attribute__((address_space(3))) void*)&As[b][sec * 512], 16, 0, 0);
    }
  };
  auto load_a_f32 = [&](int k0) {
#pragma unroll
    for (int q = 0; q < 4; ++q) {
      const float* p = Af + (arow0 + ar) * (long)K + k0 + (ac0 + q) * 8;
      areg[2 * q]     = *reinterpret_cast<const float4*>(p);
      areg[2 * q + 1] = *reinterpret_cast<const float4*>(p + 4);
    }
  };
  auto write_a = [&](int b) {
#pragma unroll
    for (int q = 0; q < 4; ++q) {
      float4 v0 = areg[2 * q], v1 = areg[2 * q + 1];
      s16x8 o;
      o[0] = (short)f2b(v0.x); o[1] = (short)f2b(v0.y);
      o[2] = (short)f2b(v0.z); o[3] = (short)f2b(v0.w);
      o[4] = (short)f2b(v1.x); o[5] = (short)f2b(v1.y);
      o[6] = (short)f2b(v1.z); o[7] = (short)f2b(v1.w);
      int dst = ar * 64 + (((ac0 + q) ^ (ar & 7)) * 8);  // same involution as read
      *(s16x8*)&As[b][dst] = o;
    }
  };
  auto compute = [&](int b) {
#pragma unroll
    for (int kk = 0; kk < 2; ++kk) {
      bf16x8 af[4], bf[4];
      const int sw = (l16 & 7) << 3;
#pragma unroll
      for (int mi = 0; mi < 4; ++mi)
        af[mi] = __builtin_bit_cast(bf16x8,
            *(const s16x8*)&As[b][(((wr * 64 + mi * 16 + l16) * 64) + kk * 32 + lh * 8) ^ sw]);
#pragma unroll
      for (int ni = 0; ni < 4; ++ni)
        bf[ni] = __builtin_bit_cast(bf16x8,
            *(const s16x8*)&Bs[b][(((wc * 64 + ni * 16 + l16) * 64) + kk * 32 + lh * 8) ^ sw]);
#pragma unroll
      for (int mi = 0; mi < 4; ++mi)
#pragma unroll
        for (int ni = 0; ni < 4; ++ni)
          acc[mi][ni] = __builtin_amdgcn_mfma_f32_16x16x32_bf16(af[mi], bf[ni], acc[mi][ni], 0, 0, 0);
    }
  };

  const int nsteps = K >> 6;
  if (A_F32) { load_a_f32(0); stage_b(0, 0); write_a(0); }
  else       { stage_a_lds(0, 0); stage_b(0, 0); }
  __syncthreads();
  int cur = 0;
  for (int s = 0; s < nsteps; ++s) {
    int nxt = cur ^ 1;
    bool has = (s + 1 < nsteps);
    if (has) {
      if (A_F32) load_a_f32((s + 1) << 6);
      else       stage_a_lds(nxt, (s + 1) << 6);
      stage_b(nxt, (s + 1) << 6);
    }
    compute(cur);
    if (A_F32 && has) write_a(nxt);
    __syncthreads();
    cur = nxt;
  }

#pragma unroll
  for (int mi = 0; mi < 4; ++mi)
#pragma unroll
    for (int ni = 0; ni < 4; ++ni)
#pragma unroll
      for (int j = 0; j < 4; ++j) {
        long row = arow0 + wr * 64 + mi * 16 + lh * 4 + j;
        long col = bcol0 + wc * 64 + ni * 16 + l16;
        float v = acc[mi][ni][j];
        if (HAS_BIAS) v += bias[col];
        if (BF16_OUT) ((unsigned short*)Cv)[row * N + col] = f2b(v);
        else          ((float*)Cv)[row * N + col] = v;
      }
}

// ---------------- GEMM3 fused with bias + row L2-norm: out = l2norm(g @ Wp^T + bo2) ----
// 128x256 tile (BN = N = 256 so a block owns full rows), BK=64, 8 waves (2x4),
// double-buffered swizzled LDS, epilogue does per-row sum-of-squares via 16-lane
// shuffle + tiny LDS, writes fp32 d_out directly.
__global__ __launch_bounds__(512) void gemm3_fused(
    const unsigned short* __restrict__ G, const unsigned short* __restrict__ Wp,
    const float* __restrict__ bo2, float* __restrict__ out) {
  __shared__ __align__(16) unsigned short As[2][128 * 64];
  __shared__ __align__(16) unsigned short Bs[2][256 * 64];
  __shared__ float ss[128][4];
  const int tid  = threadIdx.x;
  const int lane = tid & 63;
  const int w    = tid >> 6;          // 0..7
  const int wr   = w >> 2, wc = w & 3;
  const int l16  = lane & 15, lh = lane >> 4;
  const int per  = gridDim.x >> 3;
  const int bid  = blockIdx.x;
  const int wg   = (bid & 7) * per + (bid >> 3);
  const long arow0 = (long)wg * 128;
  const int srow = lane >> 3;
  const int scol = ((lane & 7) ^ srow) * 8;

  f32x4 acc[4][4];
#pragma unroll
  for (int mi = 0; mi < 4; ++mi)
#pragma unroll
    for (int ni = 0; ni < 4; ++ni) acc[mi][ni] = f32x4{0.f, 0.f, 0.f, 0.f};

  auto stage = [&](int b, int k0) {
#pragma unroll
    for (int i = 0; i < 2; ++i) {          // A: 16 sections
      int sec = i * 8 + w;
      int row = sec * 8 + srow;
      const unsigned short* ga = G + (arow0 + row) * 1024L + k0 + scol;
      __builtin_amdgcn_global_load_lds(
          (const __attribute__((address_space(1))) void*)ga,
          (__attribute__((address_space(3))) void*)&As[b][sec * 512], 16, 0, 0);
    }
#pragma unroll
    for (int i = 0; i < 4; ++i) {          // B: 32 sections (all 256 N-rows)
      int sec = i * 8 + w;
      int row = sec * 8 + srow;
      const unsigned short* gb = Wp + (long)row * 1024 + k0 + scol;
      __builtin_amdgcn_global_load_lds(
          (const __attribute__((address_space(1))) void*)gb,
          (__attribute__((address_space(3))) void*)&Bs[b][sec * 512], 16, 0, 0);
    }
  };
  auto compute = [&](int b) {
#pragma unroll
    for (int kk = 0; kk < 2; ++kk) {
      bf16x8 af[4], bf[4];
      const int sw = (l16 & 7) << 3;
#pragma unroll
      for (int mi = 0; mi < 4; ++mi)
        af[mi] = __builtin_bit_cast(bf16x8,
            *(const s16x8*)&As[b][(((wr * 64 + mi * 16 + l16) * 64) + kk * 32 + lh * 8) ^ sw]);
#pragma unroll
      for (int ni = 0; ni < 4; ++ni)
        bf[ni] = __builtin_bit_cast(bf16x8,
            *(const s16x8*)&Bs[b][(((wc * 64 + ni * 16 + l16) * 64) + kk * 32 + lh * 8) ^ sw]);
#pragma unroll
      for (int mi = 0; mi < 4; ++mi)
#pragma unroll
        for (int ni = 0; ni < 4; ++ni)
          acc[mi][ni] = __builtin_amdgcn_mfma_f32_16x16x32_bf16(af[mi], bf[ni], acc[mi][ni], 0, 0, 0);
    }
  };

  stage(0, 0);
  __syncthreads();
  int cur = 0;
  for (int s = 0; s < 16; ++s) {     // K = 1024
    int nxt = cur ^ 1;
    if (s + 1 < 16) stage(nxt, (s + 1) << 6);
    compute(cur);
    __syncthreads();
    cur = nxt;
  }

  // epilogue: add bias, row L2 norm over all 256 cols, store fp32
  float bo2v[4];
#pragma unroll
  for (int ni = 0; ni < 4; ++ni) bo2v[ni] = bo2[wc * 64 + ni * 16 + l16];
#pragma unroll
  for (int mi = 0; mi < 4; ++mi)
#pragma unroll
    for (int ni = 0; ni < 4; ++ni)
#pragma unroll
      for (int j = 0; j < 4; ++j) acc[mi][ni][j] += bo2v[ni];
#pragma unroll
  for (int mi = 0; mi < 4; ++mi)
#pragma unroll
    for (int j = 0; j < 4; ++j) {
      float p = 0.f;
#pragma unroll
      for (int ni = 0; ni < 4; ++ni) p += acc[mi][ni][j] * acc[mi][ni][j];
#pragma unroll
      for (int off = 8; off >= 1; off >>= 1) p += __shfl_xor(p, off, 64);  // over l16
      if (l16 == 0) ss[wr * 64 + mi * 16 + lh * 4 + j][wc] = p;
    }
  __syncthreads();
#pragma unroll
  for (int mi = 0; mi < 4; ++mi)
#pragma unroll
    for (int j = 0; j < 4; ++j) {
      int r = wr * 64 + mi * 16 + lh * 4 + j;
      float tot = ss[r][0] + ss[r][1] + ss[r][2] + ss[r][3];
      float inv = 1.f / fmaxf(sqrtf(tot), 1e-12f);
      long row = arow0 + r;
#pragma unroll
      for (int ni = 0; ni < 4; ++ni)
        out[row * 256 + wc * 64 + ni * 16 + l16] = acc[mi][ni][j] * inv;
    }
}

// ---------------- prep kernels (unchanged) ----------------
__global__ void prep_wall_kernel(const float* __restrict__ Wr1, const float* __restrict__ Wr2,
                                 const float* __restrict__ Wr3, const float* __restrict__ Wl,
                                 unsigned short* __restrict__ Wall) {
  int idx = blockIdx.x * 256 + threadIdx.x;
  int base = idx * 4;
  int n = base / DMODEL, k = base % DMODEL;
  const float* src = (n < 256)  ? Wr1 + (long)n * DMODEL
                   : (n < 512)  ? Wr2 + (long)(n - 256) * DMODEL
                   : (n < 768)  ? Wr3 + (long)(n - 512) * DMODEL
                                : Wl  + (long)(n - 768) * DMODEL;
  float4 v = *reinterpret_cast<const float4*>(src + k);
  ushort4 o = {f2b(v.x), f2b(v.y), f2b(v.z), f2b(v.w)};
  *reinterpret_cast<ushort4*>(Wall + base) = o;
}

__global__ void prep_G_kernel(const float* __restrict__ Wq, const float* __restrict__ Wk,
                              const float* __restrict__ bq, unsigned short* __restrict__ Wg,
                              float* __restrict__ dvec) {
  int idx = blockIdx.x * 256 + threadIdx.x;
  int n = idx >> 8, a = idx & 255;
  int h = n >> 8, b = n & 255;
  const float* wq = Wq + (long)(h * 64) * 256 + a;
  const float* wk = Wk + (long)(h * 64) * 256 + b;
  float s = 0.f;
  for (int d = 0; d < 64; ++d) s += wq[d * 256] * wk[d * 256];
  Wg[(long)n * 256 + a] = f2b(s);
  if (a == 0) {
    float t = 0.f;
    const float* bqh = bq + h * 64;
    for (int d = 0; d < 64; ++d) t += bqh[d] * wk[d * 256];
    dvec[n] = t;
  }
}

__global__ void prep_P_kernel(const float* __restrict__ Wo, const float* __restrict__ Wv,
                              const float* __restrict__ bv, const float* __restrict__ bo,
                              unsigned short* __restrict__ Wp, float* __restrict__ bo2) {
  int idx = blockIdx.x * 256 + threadIdx.x;
  int m = idx >> 10, n = idx & 1023;
  int h = n >> 8, b = n & 255;
  const float* wo = Wo + (long)m * 256 + h * 64;
  const float* wv = Wv + (long)(h * 64) * 256 + b;
  float s = 0.f;
  for (int d = 0; d < 64; ++d) s += wo[d] * wv[d * 256];
  Wp[(long)m * 1024 + n] = f2b(s);
  if (n == 0) {
    float t = bo[m];
    const float* wor = Wo + (long)m * 256;
    for (int j = 0; j < 256; ++j) t += wor[j] * bv[j];
    bo2[m] = t;
  }
}

// ---------------- per-token: 32-lane groups, 2 tokens/wave ----------------
__global__ void norm_kernel(unsigned short* __restrict__ H, unsigned short* __restrict__ q,
                            const float* __restrict__ bl, const float* __restrict__ lng,
                            const float* __restrict__ lnb) {
  int token = blockIdx.x * 8 + (threadIdx.x >> 5);
  int l = threadIdx.x & 31;
  unsigned short* row = H + (long)token * 1024;
  int b0 = l * 8;
  float h[4][8];
#pragma unroll
  for (int s = 0; s < 4; ++s) {
    s16x8 v = *(const s16x8*)(row + s * 256 + b0);
#pragma unroll
    for (int j = 0; j < 8; ++j) h[s][j] = b2f((unsigned short)v[j]);
  }
  float blv[8];
  *(float4*)&blv[0] = *(const float4*)(bl + b0);
  *(float4*)&blv[4] = *(const float4*)(bl + b0 + 4);
#pragma unroll
  for (int j = 0; j < 8; ++j) h[3][j] += blv[j];

  float ss0 = 0, ss1 = 0, ss2 = 0, s3 = 0, ss3 = 0;
#pragma unroll
  for (int j = 0; j < 8; ++j) {
    ss0 += h[0][j] * h[0][j];
    ss1 += h[1][j] * h[1][j];
    ss2 += h[2][j] * h[2][j];
    s3  += h[3][j];
    ss3 += h[3][j] * h[3][j];
  }
  ss0 = wsum32(ss0); ss1 = wsum32(ss1); ss2 = wsum32(ss2);
  s3 = wsum32(s3); ss3 = wsum32(ss3);
  float i0 = 1.f / fmaxf(sqrtf(ss0), 1e-12f);
  float i1 = 1.f / fmaxf(sqrtf(ss1), 1e-12f);
  float i2 = 1.f / fmaxf(sqrtf(ss2), 1e-12f);
  float mu = s3 * (1.f / 256.f);
  float var = ss3 * (1.f / 256.f) - mu * mu;
  float isd = rsqrtf(var + 1e-5f);
  float gv[8], bvv[8];
  *(float4*)&gv[0] = *(const float4*)(lng + b0);
  *(float4*)&gv[4] = *(const float4*)(lng + b0 + 4);
  *(float4*)&bvv[0] = *(const float4*)(lnb + b0);
  *(float4*)&bvv[4] = *(const float4*)(lnb + b0 + 4);
  float hn[8];
  float ssn = 0.f;
#pragma unroll
  for (int j = 0; j < 8; ++j) {
    hn[j] = (h[3][j] - mu) * isd * gv[j] + bvv[j];
    ssn += hn[j] * hn[j];
  }
  ssn = wsum32(ssn);
  float i3 = 1.f / fmaxf(sqrtf(ssn), 1e-12f);

  s16x8 o0, o1, o2, o3, oq;
#pragma unroll
  for (int j = 0; j < 8; ++j) {
    float f0 = h[0][j] * i0, f1 = h[1][j] * i1, f2 = h[2][j] * i2, f3 = hn[j] * i3;
    o0[j] = (short)f2b(f0); o1[j] = (short)f2b(f1);
    o2[j] = (short)f2b(f2); o3[j] = (short)f2b(f3);
    oq[j] = (short)f2b(0.25f * (f0 + f1 + f2 + f3));
  }
  *(s16x8*)(row + 0 * 256 + b0) = o0;
  *(s16x8*)(row + 1 * 256 + b0) = o1;
  *(s16x8*)(row + 2 * 256 + b0) = o2;
  *(s16x8*)(row + 3 * 256 + b0) = o3;
  *(s16x8*)(q + (long)token * 256 + b0) = oq;
}

__global__ void attn_kernel(unsigned short* __restrict__ U, const unsigned short* __restrict__ F) {
  int token = blockIdx.x * 8 + (threadIdx.x >> 5);
  int l = threadIdx.x & 31;
  unsigned short* urow = U + (long)token * 1024;
  const unsigned short* frow = F + (long)token * 1024;
  int b0 = l * 8;
  float u[4][8], f[4][8];
#pragma unroll
  for (int s = 0; s < 4; ++s) {
    s16x8 uv = *(const s16x8*)(urow + s * 256 + b0);
    s16x8 fv = *(const s16x8*)(frow + s * 256 + b0);
#pragma unroll
    for (int j = 0; j < 8; ++j) {
      u[s][j] = b2f((unsigned short)uv[j]);
      f[s][j] = b2f((unsigned short)fv[j]);
    }
  }
  float sc[4][4];
#pragma unroll
  for (int h = 0; h < 4; ++h)
#pragma unroll
    for (int k = 0; k < 4; ++k) {
      float s = 0.f;
#pragma unroll
      for (int j = 0; j < 8; ++j) s += u[h][j] * f[k][j];
      sc[h][k] = wsum32(s);
    }
#pragma unroll
  for (int h = 0; h < 4; ++h) {
    float m = fmaxf(fmaxf(sc[h][0], sc[h][1]), fmaxf(sc[h][2], sc[h][3]));
    float e0 = __expf((sc[h][0] - m) * 0.125f);
    float e1 = __expf((sc[h][1] - m) * 0.125f);
    float e2 = __expf((sc[h][2] - m) * 0.125f);
    float e3 = __expf((sc[h][3] - m) * 0.125f);
    float inv = 1.f / (e0 + e1 + e2 + e3);
    s16x8 o;
#pragma unroll
    for (int j = 0; j < 8; ++j)
      o[j] = (short)f2b((e0 * f[0][j] + e1 * f[1][j] + e2 * f[2][j] + e3 * f[3][j]) * inv);
    *(s16x8*)(urow + h * 256 + b0) = o;
  }
}

extern "C" void kernel_launch(void* const* d_in, const int* in_sizes, int n_in,
                              void* d_out, int out_size, void* d_ws, size_t ws_size,
                              hipStream_t stream) {
  const float* x   = (const float*)d_in[0];
  const float* Wr1 = (const float*)d_in[1];
  const float* Wr2 = (const float*)d_in[2];
  const float* Wr3 = (const float*)d_in[3];
  const float* Wl  = (const float*)d_in[4];
  const float* bl  = (const float*)d_in[5];
  const float* lng = (const float*)d_in[6];
  const float* lnb = (const float*)d_in[7];
  const float* Wq  = (const float*)d_in[8];
  const float* bq  = (const float*)d_in[9];
  const float* Wk  = (const float*)d_in[10];
  const float* Wv  = (const float*)d_in[12];
  const float* bv  = (const float*)d_in[13];
  const float* Wo  = (const float*)d_in[14];
  const float* bo  = (const float*)d_in[15];

  char* ws = (char*)d_ws;
  size_t off = 0;
  auto alloc = [&](size_t bytes) -> void* {
    void* p = ws + off;
    off += (bytes + 255) & ~(size_t)255;
    return p;
  };
  unsigned short* H    = (unsigned short*)alloc((size_t)TOK * 1024 * 2);  // -> feats
  unsigned short* qb   = (unsigned short*)alloc((size_t)TOK * 256 * 2);
  unsigned short* U    = (unsigned short*)alloc((size_t)TOK * 1024 * 2);  // -> g
  unsigned short* Wall = (unsigned short*)alloc((size_t)1024 * DMODEL * 2);
  unsigned short* Wg   = (unsigned short*)alloc((size_t)1024 * 256 * 2);
  unsigned short* Wp   = (unsigned short*)alloc((size_t)256 * 1024 * 2);
  float* dvec = (float*)alloc(1024 * 4);
  float* bo2  = (float*)alloc(256 * 4);

  prep_wall_kernel<<<(1024 * DMODEL) / 1024, 256, 0, stream>>>(Wr1, Wr2, Wr3, Wl, Wall);
  prep_G_kernel<<<1024, 256, 0, stream>>>(Wq, Wk, bq, Wg, dvec);
  prep_P_kernel<<<1024, 256, 0, stream>>>(Wo, Wv, bv, bo, Wp, bo2);

  // H = X @ Wall^T   [65536,1024], K=768  (A read as fp32, cast in staging)
  gemm_bt<true, false, true><<<4096, 256, 0, stream>>>((const void*)x, Wall, H, nullptr, TOK, 1024, DMODEL, 8);
  // normalize branches, build feats (in place) + q
  norm_kernel<<<TOK / 8, 256, 0, stream>>>(H, qb, bl, lng, lnb);
  // U = q @ Wg^T + dvec   [65536,1024], K=256
  gemm_bt<true, true, false><<<4096, 256, 0, stream>>>((const void*)qb, Wg, U, dvec, TOK, 1024, 256, 8);
  // attention mix: in-place U -> g
  attn_kernel<<<TOK / 8, 256, 0, stream>>>(U, H);
  // d_out = l2norm(g @ Wp^T + bo2)   [65536,256], K=1024 — fused epilogue
  gemm3_fused<<<512, 512, 0, stream>>>(U, Wp, bo2, (float*)d_out);

  (void)in_sizes; (void)n_in; (void)out_size; (void)ws_size;
}

// Round 9
// 810.589 us; speedup vs baseline: 1.0154x; 1.0154x over previous
//
#include <hip/hip_runtime.h>
#include <stdint.h>

#define TOK 65536
#define DMODEL 768

typedef short  s16x8 __attribute__((ext_vector_type(8)));
typedef __bf16 bf16x8 __attribute__((ext_vector_type(8)));
typedef float  f32x4 __attribute__((ext_vector_type(4)));

__device__ __forceinline__ float b2f(unsigned short u) {
  union { unsigned int i; float f; } v; v.i = ((unsigned int)u) << 16; return v.f;
}
__device__ __forceinline__ unsigned short f2b(float f) {
  union { float f; unsigned int i; } v; v.f = f;
  unsigned int r = v.i + 0x7fffu + ((v.i >> 16) & 1u);
  return (unsigned short)(r >> 16);
}
// HW packed f32->bf16 convert (RNE): dst = {bf16(lo), bf16(hi)}
__device__ __forceinline__ unsigned int cvt_pk_bf16(float lo, float hi) {
  unsigned int r;
  asm volatile("v_cvt_pk_bf16_f32 %0, %1, %2" : "=v"(r) : "v"(lo), "v"(hi));
  return r;
}
// reduce within a 32-lane token group (xor-based, stays inside the group)
__device__ __forceinline__ float wsum32(float v) {
#pragma unroll
  for (int off = 16; off >= 1; off >>= 1) v += __shfl_xor(v, off, 64);
  return v;
}

// ---------------- GEMM: C[M,N] = A[M,K] @ W[N,K](bf16)^T (+bias) ----------------
// 128x128 tile, BK=64, 4 waves (2x2), mfma_f32_16x16x32_bf16, T2 XOR-swizzled LDS
// (both-sides involution), double-buffer: STAGE(t+1) issued BEFORE compute(t);
// ONE __syncthreads per K-step. A_F32: reg-stage fp32 A (load -> v_cvt_pk_bf16_f32
// -> swizzled 16B ds_write). R7 lesson: hand-rolled f2b here was ~160 VALU/thread
// per K-step (> MFMA time); cvt_pk cuts it to 16.
template <bool BF16_OUT, bool HAS_BIAS, bool A_F32>
__global__ __launch_bounds__(256) void gemm_bt(const void* __restrict__ Av,
                        const unsigned short* __restrict__ W,
                        void* __restrict__ Cv,
                        const float* __restrict__ bias,
                        int M, int N, int K, int nt) {
  __shared__ __align__(16) unsigned short As[2][128 * 64];
  __shared__ __align__(16) unsigned short Bs[2][128 * 64];
  const int tid  = threadIdx.x;
  const int lane = tid & 63;
  const int w    = tid >> 6;      // wave 0..3
  const int wr   = w >> 1, wc = w & 1;
  const int l16  = lane & 15, lh = lane >> 4;

  const int per = gridDim.x >> 3;       // gridDim.x % 8 == 0
  const int bid = blockIdx.x;
  const int wg  = (bid & 7) * per + (bid >> 3);
  const long arow0 = (long)(wg / nt) * 128;
  const long bcol0 = (long)(wg % nt) * 128;

  const int srow = lane >> 3;                   // 0..7 within an 8-row section
  const int scol = ((lane & 7) ^ srow) * 8;     // pre-swizzled global chunk

  // f32-A reg staging: thread -> (row, 4 chunks of 8 elems)
  const int ar  = tid >> 1;          // 0..127
  const int ac0 = (tid & 1) * 4;     // chunk base 0 or 4

  const unsigned short* Au = (const unsigned short*)Av;
  const float* Af = (const float*)Av;

  f32x4 acc[4][4];
#pragma unroll
  for (int mi = 0; mi < 4; ++mi)
#pragma unroll
    for (int ni = 0; ni < 4; ++ni) acc[mi][ni] = f32x4{0.f, 0.f, 0.f, 0.f};

  float4 areg[8];

  auto stage_b = [&](int b, int k0) {
#pragma unroll
    for (int i = 0; i < 4; ++i) {
      int sec = i * 4 + w;
      int row = sec * 8 + srow;
      const unsigned short* gb = W + (bcol0 + row) * (long)K + k0 + scol;
      __builtin_amdgcn_global_load_lds(
          (const __attribute__((address_space(1))) void*)gb,
          (__attribute__((address_space(3))) void*)&Bs[b][sec * 512], 16, 0, 0);
    }
  };
  auto stage_a_lds = [&](int b, int k0) {
#pragma unroll
    for (int i = 0; i < 4; ++i) {
      int sec = i * 4 + w;
      int row = sec * 8 + srow;
      const unsigned short* ga = Au + (arow0 + row) * (long)K + k0 + scol;
      __builtin_amdgcn_global_load_lds(
          (const __attribute__((address_space(1))) void*)ga,
          (__attribute__((address_space(3))) void*)&As[b][sec * 512], 16, 0, 0);
    }
  };
  auto load_a_f32 = [&](int k0) {
#pragma unroll
    for (int q = 0; q < 4; ++q) {
      const float* p = Af + (arow0 + ar) * (long)K + k0 + (ac0 + q) * 8;
      areg[2 * q]     = *reinterpret_cast<const float4*>(p);
      areg[2 * q + 1] = *reinterpret_cast<const float4*>(p + 4);
    }
  };
  auto write_a = [&](int b) {
#pragma unroll
    for (int q = 0; q < 4; ++q) {
      float4 v0 = areg[2 * q], v1 = areg[2 * q + 1];
      uint4 o;
      o.x = cvt_pk_bf16(v0.x, v0.y);
      o.y = cvt_pk_bf16(v0.z, v0.w);
      o.z = cvt_pk_bf16(v1.x, v1.y);
      o.w = cvt_pk_bf16(v1.z, v1.w);
      int dst = ar * 64 + (((ac0 + q) ^ (ar & 7)) * 8);  // same involution as read
      *(uint4*)&As[b][dst] = o;
    }
  };
  auto compute = [&](int b) {
#pragma unroll
    for (int kk = 0; kk < 2; ++kk) {
      bf16x8 af[4], bf[4];
      const int sw = (l16 & 7) << 3;
#pragma unroll
      for (int mi = 0; mi < 4; ++mi)
        af[mi] = __builtin_bit_cast(bf16x8,
            *(const s16x8*)&As[b][(((wr * 64 + mi * 16 + l16) * 64) + kk * 32 + lh * 8) ^ sw]);
#pragma unroll
      for (int ni = 0; ni < 4; ++ni)
        bf[ni] = __builtin_bit_cast(bf16x8,
            *(const s16x8*)&Bs[b][(((wc * 64 + ni * 16 + l16) * 64) + kk * 32 + lh * 8) ^ sw]);
#pragma unroll
      for (int mi = 0; mi < 4; ++mi)
#pragma unroll
        for (int ni = 0; ni < 4; ++ni)
          acc[mi][ni] = __builtin_amdgcn_mfma_f32_16x16x32_bf16(af[mi], bf[ni], acc[mi][ni], 0, 0, 0);
    }
  };

  const int nsteps = K >> 6;
  if (A_F32) { load_a_f32(0); stage_b(0, 0); write_a(0); }
  else       { stage_a_lds(0, 0); stage_b(0, 0); }
  __syncthreads();
  int cur = 0;
  for (int s = 0; s < nsteps; ++s) {
    int nxt = cur ^ 1;
    bool has = (s + 1 < nsteps);
    if (has) {
      if (A_F32) load_a_f32((s + 1) << 6);
      else       stage_a_lds(nxt, (s + 1) << 6);
      stage_b(nxt, (s + 1) << 6);
    }
    compute(cur);
    if (A_F32 && has) write_a(nxt);
    __syncthreads();
    cur = nxt;
  }

#pragma unroll
  for (int mi = 0; mi < 4; ++mi)
#pragma unroll
    for (int ni = 0; ni < 4; ++ni)
#pragma unroll
      for (int j = 0; j < 4; ++j) {
        long row = arow0 + wr * 64 + mi * 16 + lh * 4 + j;
        long col = bcol0 + wc * 64 + ni * 16 + l16;
        float v = acc[mi][ni][j];
        if (HAS_BIAS) v += bias[col];
        if (BF16_OUT) ((unsigned short*)Cv)[row * N + col] = f2b(v);
        else          ((float*)Cv)[row * N + col] = v;
      }
}

// ---------------- GEMM3 fused with bias + row L2-norm: out = l2norm(g @ Wp^T + bo2) ----
__global__ __launch_bounds__(512) void gemm3_fused(
    const unsigned short* __restrict__ G, const unsigned short* __restrict__ Wp,
    const float* __restrict__ bo2, float* __restrict__ out) {
  __shared__ __align__(16) unsigned short As[2][128 * 64];
  __shared__ __align__(16) unsigned short Bs[2][256 * 64];
  __shared__ float ss[128][4];
  const int tid  = threadIdx.x;
  const int lane = tid & 63;
  const int w    = tid >> 6;          // 0..7
  const int wr   = w >> 2, wc = w & 3;
  const int l16  = lane & 15, lh = lane >> 4;
  const int per  = gridDim.x >> 3;
  const int bid  = blockIdx.x;
  const int wg   = (bid & 7) * per + (bid >> 3);
  const long arow0 = (long)wg * 128;
  const int srow = lane >> 3;
  const int scol = ((lane & 7) ^ srow) * 8;

  f32x4 acc[4][4];
#pragma unroll
  for (int mi = 0; mi < 4; ++mi)
#pragma unroll
    for (int ni = 0; ni < 4; ++ni) acc[mi][ni] = f32x4{0.f, 0.f, 0.f, 0.f};

  auto stage = [&](int b, int k0) {
#pragma unroll
    for (int i = 0; i < 2; ++i) {          // A: 16 sections
      int sec = i * 8 + w;
      int row = sec * 8 + srow;
      const unsigned short* ga = G + (arow0 + row) * 1024L + k0 + scol;
      __builtin_amdgcn_global_load_lds(
          (const __attribute__((address_space(1))) void*)ga,
          (__attribute__((address_space(3))) void*)&As[b][sec * 512], 16, 0, 0);
    }
#pragma unroll
    for (int i = 0; i < 4; ++i) {          // B: 32 sections (all 256 N-rows)
      int sec = i * 8 + w;
      int row = sec * 8 + srow;
      const unsigned short* gb = Wp + (long)row * 1024 + k0 + scol;
      __builtin_amdgcn_global_load_lds(
          (const __attribute__((address_space(1))) void*)gb,
          (__attribute__((address_space(3))) void*)&Bs[b][sec * 512], 16, 0, 0);
    }
  };
  auto compute = [&](int b) {
#pragma unroll
    for (int kk = 0; kk < 2; ++kk) {
      bf16x8 af[4], bf[4];
      const int sw = (l16 & 7) << 3;
#pragma unroll
      for (int mi = 0; mi < 4; ++mi)
        af[mi] = __builtin_bit_cast(bf16x8,
            *(const s16x8*)&As[b][(((wr * 64 + mi * 16 + l16) * 64) + kk * 32 + lh * 8) ^ sw]);
#pragma unroll
      for (int ni = 0; ni < 4; ++ni)
        bf[ni] = __builtin_bit_cast(bf16x8,
            *(const s16x8*)&Bs[b][(((wc * 64 + ni * 16 + l16) * 64) + kk * 32 + lh * 8) ^ sw]);
#pragma unroll
      for (int mi = 0; mi < 4; ++mi)
#pragma unroll
        for (int ni = 0; ni < 4; ++ni)
          acc[mi][ni] = __builtin_amdgcn_mfma_f32_16x16x32_bf16(af[mi], bf[ni], acc[mi][ni], 0, 0, 0);
    }
  };

  stage(0, 0);
  __syncthreads();
  int cur = 0;
  for (int s = 0; s < 16; ++s) {     // K = 1024
    int nxt = cur ^ 1;
    if (s + 1 < 16) stage(nxt, (s + 1) << 6);
    compute(cur);
    __syncthreads();
    cur = nxt;
  }

  // epilogue: add bias, row L2 norm over all 256 cols, store fp32
  float bo2v[4];
#pragma unroll
  for (int ni = 0; ni < 4; ++ni) bo2v[ni] = bo2[wc * 64 + ni * 16 + l16];
#pragma unroll
  for (int mi = 0; mi < 4; ++mi)
#pragma unroll
    for (int ni = 0; ni < 4; ++ni)
#pragma unroll
      for (int j = 0; j < 4; ++j) acc[mi][ni][j] += bo2v[ni];
#pragma unroll
  for (int mi = 0; mi < 4; ++mi)
#pragma unroll
    for (int j = 0; j < 4; ++j) {
      float p = 0.f;
#pragma unroll
      for (int ni = 0; ni < 4; ++ni) p += acc[mi][ni][j] * acc[mi][ni][j];
#pragma unroll
      for (int off = 8; off >= 1; off >>= 1) p += __shfl_xor(p, off, 64);  // over l16
      if (l16 == 0) ss[wr * 64 + mi * 16 + lh * 4 + j][wc] = p;
    }
  __syncthreads();
#pragma unroll
  for (int mi = 0; mi < 4; ++mi)
#pragma unroll
    for (int j = 0; j < 4; ++j) {
      int r = wr * 64 + mi * 16 + lh * 4 + j;
      float tot = ss[r][0] + ss[r][1] + ss[r][2] + ss[r][3];
      float inv = 1.f / fmaxf(sqrtf(tot), 1e-12f);
      long row = arow0 + r;
#pragma unroll
      for (int ni = 0; ni < 4; ++ni)
        out[row * 256 + wc * 64 + ni * 16 + l16] = acc[mi][ni][j] * inv;
    }
}

// ---------------- prep kernels ----------------
__global__ void prep_wall_kernel(const float* __restrict__ Wr1, const float* __restrict__ Wr2,
                                 const float* __restrict__ Wr3, const float* __restrict__ Wl,
                                 unsigned short* __restrict__ Wall) {
  int idx = blockIdx.x * 256 + threadIdx.x;
  int base = idx * 4;
  int n = base / DMODEL, k = base % DMODEL;
  const float* src = (n < 256)  ? Wr1 + (long)n * DMODEL
                   : (n < 512)  ? Wr2 + (long)(n - 256) * DMODEL
                   : (n < 768)  ? Wr3 + (long)(n - 512) * DMODEL
                                : Wl  + (long)(n - 768) * DMODEL;
  float4 v = *reinterpret_cast<const float4*>(src + k);
  ushort4 o = {f2b(v.x), f2b(v.y), f2b(v.z), f2b(v.w)};
  *reinterpret_cast<ushort4*>(Wall + base) = o;
}

__global__ void prep_G_kernel(const float* __restrict__ Wq, const float* __restrict__ Wk,
                              const float* __restrict__ bq, unsigned short* __restrict__ Wg,
                              float* __restrict__ dvec) {
  int idx = blockIdx.x * 256 + threadIdx.x;
  int n = idx >> 8, a = idx & 255;
  int h = n >> 8, b = n & 255;
  const float* wq = Wq + (long)(h * 64) * 256 + a;
  const float* wk = Wk + (long)(h * 64) * 256 + b;
  float s = 0.f;
  for (int d = 0; d < 64; ++d) s += wq[d * 256] * wk[d * 256];
  Wg[(long)n * 256 + a] = f2b(s);
  if (a == 0) {
    float t = 0.f;
    const float* bqh = bq + h * 64;
    for (int d = 0; d < 64; ++d) t += bqh[d] * wk[d * 256];
    dvec[n] = t;
  }
}

__global__ void prep_P_kernel(const float* __restrict__ Wo, const float* __restrict__ Wv,
                              const float* __restrict__ bv, const float* __restrict__ bo,
                              unsigned short* __restrict__ Wp, float* __restrict__ bo2) {
  int idx = blockIdx.x * 256 + threadIdx.x;
  int m = idx >> 10, n = idx & 1023;
  int h = n >> 8, b = n & 255;
  const float* wo = Wo + (long)m * 256 + h * 64;
  const float* wv = Wv + (long)(h * 64) * 256 + b;
  float s = 0.f;
  for (int d = 0; d < 64; ++d) s += wo[d] * wv[d * 256];
  Wp[(long)m * 1024 + n] = f2b(s);
  if (n == 0) {
    float t = bo[m];
    const float* wor = Wo + (long)m * 256;
    for (int j = 0; j < 256; ++j) t += wor[j] * bv[j];
    bo2[m] = t;
  }
}

// ---------------- per-token: 32-lane groups, 2 tokens/wave ----------------
__global__ void norm_kernel(unsigned short* __restrict__ H, unsigned short* __restrict__ q,
                            const float* __restrict__ bl, const float* __restrict__ lng,
                            const float* __restrict__ lnb) {
  int token = blockIdx.x * 8 + (threadIdx.x >> 5);
  int l = threadIdx.x & 31;
  unsigned short* row = H + (long)token * 1024;
  int b0 = l * 8;
  float h[4][8];
#pragma unroll
  for (int s = 0; s < 4; ++s) {
    s16x8 v = *(const s16x8*)(row + s * 256 + b0);
#pragma unroll
    for (int j = 0; j < 8; ++j) h[s][j] = b2f((unsigned short)v[j]);
  }
  float blv[8];
  *(float4*)&blv[0] = *(const float4*)(bl + b0);
  *(float4*)&blv[4] = *(const float4*)(bl + b0 + 4);
#pragma unroll
  for (int j = 0; j < 8; ++j) h[3][j] += blv[j];

  float ss0 = 0, ss1 = 0, ss2 = 0, s3 = 0, ss3 = 0;
#pragma unroll
  for (int j = 0; j < 8; ++j) {
    ss0 += h[0][j] * h[0][j];
    ss1 += h[1][j] * h[1][j];
    ss2 += h[2][j] * h[2][j];
    s3  += h[3][j];
    ss3 += h[3][j] * h[3][j];
  }
  ss0 = wsum32(ss0); ss1 = wsum32(ss1); ss2 = wsum32(ss2);
  s3 = wsum32(s3); ss3 = wsum32(ss3);
  float i0 = 1.f / fmaxf(sqrtf(ss0), 1e-12f);
  float i1 = 1.f / fmaxf(sqrtf(ss1), 1e-12f);
  float i2 = 1.f / fmaxf(sqrtf(ss2), 1e-12f);
  float mu = s3 * (1.f / 256.f);
  float var = ss3 * (1.f / 256.f) - mu * mu;
  float isd = rsqrtf(var + 1e-5f);
  float gv[8], bvv[8];
  *(float4*)&gv[0] = *(const float4*)(lng + b0);
  *(float4*)&gv[4] = *(const float4*)(lng + b0 + 4);
  *(float4*)&bvv[0] = *(const float4*)(lnb + b0);
  *(float4*)&bvv[4] = *(const float4*)(lnb + b0 + 4);
  float hn[8];
  float ssn = 0.f;
#pragma unroll
  for (int j = 0; j < 8; ++j) {
    hn[j] = (h[3][j] - mu) * isd * gv[j] + bvv[j];
    ssn += hn[j] * hn[j];
  }
  ssn = wsum32(ssn);
  float i3 = 1.f / fmaxf(sqrtf(ssn), 1e-12f);

  s16x8 o0, o1, o2, o3, oq;
#pragma unroll
  for (int j = 0; j < 8; ++j) {
    float f0 = h[0][j] * i0, f1 = h[1][j] * i1, f2 = h[2][j] * i2, f3 = hn[j] * i3;
    o0[j] = (short)f2b(f0); o1[j] = (short)f2b(f1);
    o2[j] = (short)f2b(f2); o3[j] = (short)f2b(f3);
    oq[j] = (short)f2b(0.25f * (f0 + f1 + f2 + f3));
  }
  *(s16x8*)(row + 0 * 256 + b0) = o0;
  *(s16x8*)(row + 1 * 256 + b0) = o1;
  *(s16x8*)(row + 2 * 256 + b0) = o2;
  *(s16x8*)(row + 3 * 256 + b0) = o3;
  *(s16x8*)(q + (long)token * 256 + b0) = oq;
}

__global__ void attn_kernel(unsigned short* __restrict__ U, const unsigned short* __restrict__ F) {
  int token = blockIdx.x * 8 + (threadIdx.x >> 5);
  int l = threadIdx.x & 31;
  unsigned short* urow = U + (long)token * 1024;
  const unsigned short* frow = F + (long)token * 1024;
  int b0 = l * 8;
  float u[4][8], f[4][8];
#pragma unroll
  for (int s = 0; s < 4; ++s) {
    s16x8 uv = *(const s16x8*)(urow + s * 256 + b0);
    s16x8 fv = *(const s16x8*)(frow + s * 256 + b0);
#pragma unroll
    for (int j = 0; j < 8; ++j) {
      u[s][j] = b2f((unsigned short)uv[j]);
      f[s][j] = b2f((unsigned short)fv[j]);
    }
  }
  float sc[4][4];
#pragma unroll
  for (int h = 0; h < 4; ++h)
#pragma unroll
    for (int k = 0; k < 4; ++k) {
      float s = 0.f;
#pragma unroll
      for (int j = 0; j < 8; ++j) s += u[h][j] * f[k][j];
      sc[h][k] = wsum32(s);
    }
#pragma unroll
  for (int h = 0; h < 4; ++h) {
    float m = fmaxf(fmaxf(sc[h][0], sc[h][1]), fmaxf(sc[h][2], sc[h][3]));
    float e0 = __expf((sc[h][0] - m) * 0.125f);
    float e1 = __expf((sc[h][1] - m) * 0.125f);
    float e2 = __expf((sc[h][2] - m) * 0.125f);
    float e3 = __expf((sc[h][3] - m) * 0.125f);
    float inv = 1.f / (e0 + e1 + e2 + e3);
    s16x8 o;
#pragma unroll
    for (int j = 0; j < 8; ++j)
      o[j] = (short)f2b((e0 * f[0][j] + e1 * f[1][j] + e2 * f[2][j] + e3 * f[3][j]) * inv);
    *(s16x8*)(urow + h * 256 + b0) = o;
  }
}

extern "C" void kernel_launch(void* const* d_in, const int* in_sizes, int n_in,
                              void* d_out, int out_size, void* d_ws, size_t ws_size,
                              hipStream_t stream) {
  const float* x   = (const float*)d_in[0];
  const float* Wr1 = (const float*)d_in[1];
  const float* Wr2 = (const float*)d_in[2];
  const float* Wr3 = (const float*)d_in[3];
  const float* Wl  = (const float*)d_in[4];
  const float* bl  = (const float*)d_in[5];
  const float* lng = (const float*)d_in[6];
  const float* lnb = (const float*)d_in[7];
  const float* Wq  = (const float*)d_in[8];
  const float* bq  = (const float*)d_in[9];
  const float* Wk  = (const float*)d_in[10];
  const float* Wv  = (const float*)d_in[12];
  const float* bv  = (const float*)d_in[13];
  const float* Wo  = (const float*)d_in[14];
  const float* bo  = (const float*)d_in[15];

  char* ws = (char*)d_ws;
  size_t off = 0;
  auto alloc = [&](size_t bytes) -> void* {
    void* p = ws + off;
    off += (bytes + 255) & ~(size_t)255;
    return p;
  };
  unsigned short* H    = (unsigned short*)alloc((size_t)TOK * 1024 * 2);  // -> feats
  unsigned short* qb   = (unsigned short*)alloc((size_t)TOK * 256 * 2);
  unsigned short* U    = (unsigned short*)alloc((size_t)TOK * 1024 * 2);  // -> g
  unsigned short* Wall = (unsigned short*)alloc((size_t)1024 * DMODEL * 2);
  unsigned short* Wg   = (unsigned short*)alloc((size_t)1024 * 256 * 2);
  unsigned short* Wp   = (unsigned short*)alloc((size_t)256 * 1024 * 2);
  float* dvec = (float*)alloc(1024 * 4);
  float* bo2  = (float*)alloc(256 * 4);

  prep_wall_kernel<<<(1024 * DMODEL) / 1024, 256, 0, stream>>>(Wr1, Wr2, Wr3, Wl, Wall);
  prep_G_kernel<<<1024, 256, 0, stream>>>(Wq, Wk, bq, Wg, dvec);
  prep_P_kernel<<<1024, 256, 0, stream>>>(Wo, Wv, bv, bo, Wp, bo2);

  // H = X @ Wall^T   [65536,1024], K=768  (A read as fp32, cvt_pk in staging)
  gemm_bt<true, false, true><<<4096, 256, 0, stream>>>((const void*)x, Wall, H, nullptr, TOK, 1024, DMODEL, 8);
  // normalize branches, build feats (in place) + q
  norm_kernel<<<TOK / 8, 256, 0, stream>>>(H, qb, bl, lng, lnb);
  // U = q @ Wg^T + dvec   [65536,1024], K=256
  gemm_bt<true, true, false><<<4096, 256, 0, stream>>>((const void*)qb, Wg, U, dvec, TOK, 1024, 256, 8);
  // attention mix: in-place U -> g
  attn_kernel<<<TOK / 8, 256, 0, stream>>>(U, H);
  // d_out = l2norm(g @ Wp^T + bo2)   [65536,256], K=1024 — fused epilogue
  gemm3_fused<<<512, 512, 0, stream>>>(U, Wp, bo2, (float*)d_out);

  (void)in_sizes; (void)n_in; (void)out_size; (void)ws_size;
}